// Round 12
// baseline (196.152 us; speedup 1.0000x reference)
//
#include <hip/hip_runtime.h>
#include <cstdint>

#define NB 64
#define NC 256
#define HW 784              // 28*28
#define NPIX (NB*HW)        // 50176
#define NELEM ((size_t)NB*NC*HW)

#define HALO_ROWS 122       // pixels p0-29 .. p0+92 for a 64px tile
#define A_BYTES (HALO_ROWS*256)       // 31232
#define ZERO_OFF A_BYTES              // 256B zero row
#define W_LDS_OFF (A_BYTES + 256)     // 31488
#define W_BUF_SZ 16384                // one quarter-tap (2 cin-chunks)
#define CONV_LDS (W_LDS_OFF + 2*W_BUF_SZ)  // 64256

typedef int v4i  __attribute__((ext_vector_type(4)));
typedef int v16i __attribute__((ext_vector_type(16)));

union U16 { signed char b[16]; int4 v; };

// ---------------------------------------------------------------------------
// alpha = mean|w| per (conv, cout).
// ---------------------------------------------------------------------------
__global__ __launch_bounds__(256) void alpha_k(
    const float* __restrict__ w1, const float* __restrict__ w2,
    float* __restrict__ al1, float* __restrict__ al2) {
  int blk = blockIdx.x;
  int conv = blk >> 8, cout = blk & 255;
  const float* w = (conv ? w2 : w1) + (size_t)cout * 2304;
  int t = threadIdx.x;
  float s = 0.0f;
  for (int i = t; i < 2304; i += 256) s += fabsf(w[i]);
  __shared__ float red[256];
  red[t] = s;
  __syncthreads();
  for (int st = 128; st > 0; st >>= 1) {
    if (t < st) red[t] += red[t + st];
    __syncthreads();
  }
  if (t == 0) (conv ? al2 : al1)[cout] = red[0] / 2304.0f;
}

// ---------------------------------------------------------------------------
// Pack weights into MFMA B-fragment order: Wf[tap][chunk(8)][cgroup(8)][lane(64)][16]
// ---------------------------------------------------------------------------
__global__ __launch_bounds__(256) void wfrag_k(
    const float* __restrict__ w1, const float* __restrict__ w2,
    signed char* __restrict__ Wf1, signed char* __restrict__ Wf2) {
  int bi = blockIdx.x;            // 144 = 2 conv x 9 tap x 8 cgroup
  int conv = bi / 72, r = bi % 72, tap = r >> 3, cg = r & 7;
  const float* w = conv ? w2 : w1;
  signed char* Wf = conv ? Wf2 : Wf1;
  int t = threadIdx.x;
  for (int e = t; e < 512; e += 256) {
    int c = e >> 6, lane = e & 63;
    int cout = cg * 32 + (lane & 31);
    int cin0 = c * 32 + (lane >> 5) * 16;
    U16 u;
#pragma unroll
    for (int bb = 0; bb < 16; ++bb) {
      float v = w[((size_t)cout * 256 + cin0 + bb) * 9 + tap];
      u.b[bb] = v > 0.f ? 1 : (v < 0.f ? -1 : 0);
    }
    *(int4*)(Wf + ((((size_t)tap * 8 + c) * 8 + cg) * 64 + lane) * 16) = u.v;
  }
}

// ---------------------------------------------------------------------------
// x (NCHW f32) -> int8 signs, pixel-major [p][256]. LDS transpose, coalesced.
// ---------------------------------------------------------------------------
__global__ __launch_bounds__(256) void pack_x(
    const float* __restrict__ in, signed char* __restrict__ A) {
  __shared__ float tile[256 * 33];
  int t = threadIdx.x;
  int P0 = blockIdx.x * 32;
  int pl = t & 31, c0 = t >> 5;
  int P = P0 + pl;
  int b = P / HW, hw = P - b * HW;
  size_t base = (size_t)b * (NC * HW) + (size_t)c0 * HW + hw;
#pragma unroll
  for (int i = 0; i < 32; ++i)
    tile[(i * 8 + c0) * 33 + pl] = in[base + (size_t)i * 8 * HW];
  __syncthreads();
  int g = t >> 4, pls = t & 15;
#pragma unroll
  for (int ph = 0; ph < 2; ++ph) {
    int pp = ph * 16 + pls;
    U16 u;
#pragma unroll
    for (int bb = 0; bb < 16; ++bb) {
      float v = tile[(g * 16 + bb) * 33 + pp];
      u.b[bb] = v > 0.f ? 1 : (v < 0.f ? -1 : 0);
    }
    *(int4*)(A + (size_t)(P0 + pp) * 256 + g * 16) = u.v;
  }
}

// ---------------------------------------------------------------------------
// int8 MFMA conv 3x3 pad 1 + per-wave i32 BN-stat partials.
// Block: 64 px x 256 co, 4 waves (each 64px x 64co), grid 784.
// W is staged through LDS per quarter-tap (16KB, double-buffered, T14
// reg-split: global->reg at phase start, ds_write after compute, one
// barrier per phase, 36 phases). Hot loop reads ONLY LDS -> the L2 W
// stream is decoupled from the MFMA dependency chain.
// Invalid taps read a zeroed LDS row.
// ---------------------------------------------------------------------------
__global__ __launch_bounds__(256, 2) void conv_mfma(
    const signed char* __restrict__ A, const signed char* __restrict__ Wf,
    short* __restrict__ dotb,
    int* __restrict__ pd, int* __restrict__ pq) {
  __shared__ signed char smem[CONV_LDS];
  signed char* As = smem;
  signed char* Wlds = smem + W_LDS_OFF;

  int t = threadIdx.x;
  int lane = t & 63, wid = t >> 6;
  int mblk = blockIdx.x;
  int p0 = mblk * 64;
  int khalf = lane >> 5;

  // stage A halo rows p0-29 .. p0+92 with granule swizzle (key = pixel&15)
  {
    const signed char* src = A + (size_t)(p0 - 29) * 256;
#pragma unroll
    for (int i = 0; i < 8; ++i) {
      int off = i * 4096 + t * 16;
      if (off < A_BYTES) {
        int4 d = *(const int4*)(src + off);
        int r = off >> 8, g = (off >> 4) & 15;
        int gs = g ^ ((r + 3) & 15);    // (p0-29+r)&15 with p0%16==0
        *(int4*)(As + r * 256 + gs * 16) = d;
      }
    }
    if (t < 16) { int4 z = {0, 0, 0, 0}; *(int4*)(As + ZERO_OFF + t * 16) = z; }
  }
  // stage W phase 0 into buffer 0 (direct reg->LDS)
  {
#pragma unroll
    for (int i = 0; i < 4; ++i) {
      int off = i * 4096 + t * 16;
      int4 d = *(const int4*)(Wf + off);
      *(int4*)(Wlds + off) = d;
    }
  }

  // per-lane pixel geometry for the 2 M-fragments (same for all 4 waves)
  int prow[2], hh[2], ww[2];
#pragma unroll
  for (int i = 0; i < 2; ++i) {
    int p = p0 + i * 32 + (lane & 31);
    prow[i] = p;
    int hw = p % HW;
    hh[i] = hw / 28;
    ww[i] = hw - hh[i] * 28;
  }
  __syncthreads();

  v16i acc[2][2];
  {
    v16i z = {0};
    acc[0][0] = z; acc[0][1] = z; acc[1][0] = z; acc[1][1] = z;
  }

  int rb0 = 0, rb1 = 0, kk0 = 0, kk1 = 0;
  // W ds_read base for this wave's cgroup pair (2*wid, 2*wid+1)
  const int wrd_off = wid * 2048 + lane * 16;

  for (int ph = 0; ph < 36; ++ph) {   // ph = tap*4 + qc
    const int cur = ph & 1;

    // new tap: compute A address tables
    if ((ph & 3) == 0) {
      const int tap = ph >> 2;
      const int ky = (tap >= 3) + (tap >= 6);
      const int kx = tap - 3 * ky;
      const int dlt = (ky - 1) * 28 + (kx - 1);
      int hp = hh[0] + ky - 1, wp = ww[0] + kx - 1;
      bool val = ((unsigned)hp < 28u) && ((unsigned)wp < 28u);
      int pr = prow[0] + dlt;
      rb0 = val ? (pr - (p0 - 29)) * 256 : ZERO_OFF;
      kk0 = val ? ((pr & 15) << 4) : 0;
      hp = hh[1] + ky - 1; wp = ww[1] + kx - 1;
      val = ((unsigned)hp < 28u) && ((unsigned)wp < 28u);
      pr = prow[1] + dlt;
      rb1 = val ? (pr - (p0 - 29)) * 256 : ZERO_OFF;
      kk1 = val ? ((pr & 15) << 4) : 0;
    }

    // T14 issue-early: global loads for phase ph+1 into registers
    int4 wreg0, wreg1, wreg2, wreg3;
    if (ph < 35) {
      const signed char* wsrc = Wf + (size_t)(ph + 1) * 16384 + t * 16;
      wreg0 = *(const int4*)(wsrc);
      wreg1 = *(const int4*)(wsrc + 4096);
      wreg2 = *(const int4*)(wsrc + 8192);
      wreg3 = *(const int4*)(wsrc + 12288);
    }

    // compute the 2 cin-chunks of this quarter-tap (LDS only)
    const signed char* wbuf = Wlds + cur * W_BUF_SZ;
#pragma unroll
    for (int cl = 0; cl < 2; ++cl) {
      const int chunk = (ph & 3) * 2 + cl;
      const int gl4 = ((chunk * 2 + khalf) << 4);
      v4i a0 = *(const v4i*)(As + rb0 + (gl4 ^ kk0));
      v4i a1 = *(const v4i*)(As + rb1 + (gl4 ^ kk1));
      v4i w0 = *(const v4i*)(wbuf + cl * 8192 + wrd_off);
      v4i w1 = *(const v4i*)(wbuf + cl * 8192 + wrd_off + 1024);
      acc[0][0] = __builtin_amdgcn_mfma_i32_32x32x32_i8(a0, w0, acc[0][0], 0, 0, 0);
      acc[0][1] = __builtin_amdgcn_mfma_i32_32x32x32_i8(a0, w1, acc[0][1], 0, 0, 0);
      acc[1][0] = __builtin_amdgcn_mfma_i32_32x32x32_i8(a1, w0, acc[1][0], 0, 0, 0);
      acc[1][1] = __builtin_amdgcn_mfma_i32_32x32x32_i8(a1, w1, acc[1][1], 0, 0, 0);
    }

    // T14 write-late: ds_write prefetched W into the other buffer, barrier
    if (ph < 35) {
      signed char* wdst = Wlds + (cur ^ 1) * W_BUF_SZ + t * 16;
      *(int4*)(wdst)         = wreg0;
      *(int4*)(wdst + 4096)  = wreg1;
      *(int4*)(wdst + 8192)  = wreg2;
      *(int4*)(wdst + 12288) = wreg3;
    }
    __syncthreads();
  }

  // stats: per-cout partial sums of dot and dot^2 over this block's 64 rows
#pragma unroll
  for (int j = 0; j < 2; ++j) {
    int s = 0, sq = 0;
#pragma unroll
    for (int i = 0; i < 2; ++i)
#pragma unroll
      for (int q = 0; q < 16; ++q) {
        int v = acc[i][j][q];
        s += v; sq += v * v;
      }
    s += __shfl_xor(s, 32); sq += __shfl_xor(sq, 32);
    if (lane < 32) {
      pd[mblk * 256 + wid * 64 + j * 32 + lane] = s;
      pq[mblk * 256 + wid * 64 + j * 32 + lane] = sq;
    }
  }

  // store dot int16, pixel-major [p][256]
#pragma unroll
  for (int i = 0; i < 2; ++i) {
    int pr = p0 + i * 32 + 4 * khalf;
#pragma unroll
    for (int j = 0; j < 2; ++j) {
      int cb = wid * 64 + j * 32;
#pragma unroll
      for (int q = 0; q < 16; ++q) {
        int row = pr + (q & 3) + 8 * (q >> 2);
        dotb[(size_t)row * 256 + cb + (lane & 31)] = (short)acc[i][j][q];
      }
    }
  }
}

// ---------------------------------------------------------------------------
// Finalize BN from i32 partials (784 rows). One block per channel.
// ---------------------------------------------------------------------------
__global__ __launch_bounds__(256) void bn_finalize(
    const int* __restrict__ pd, const int* __restrict__ pq,
    const float* __restrict__ alpha, const float* __restrict__ gamma,
    const float* __restrict__ beta, float* __restrict__ scale,
    float* __restrict__ shift) {
  int c = blockIdx.x, t = threadIdx.x;
  long long D = 0, D2 = 0;
  for (int r = t; r < 784; r += 256) {
    D  += (long long)pd[r * 256 + c];
    D2 += (long long)pq[r * 256 + c];
  }
  __shared__ long long rd[256], rq[256];
  rd[t] = D; rq[t] = D2;
  __syncthreads();
  for (int st = 128; st > 0; st >>= 1) {
    if (t < st) { rd[t] += rd[t + st]; rq[t] += rq[t + st]; }
    __syncthreads();
  }
  if (t == 0) {
    float sc = 0.1f * alpha[c];
    const float invN = 1.0f / (float)(NB * HW);
    float md  = (float)rd[0] * invN;
    float ex2 = (float)rq[0] * invN;
    float var = sc * sc * (ex2 - md * md);
    float rs = rsqrtf(var + 1e-5f);
    float g = gamma[c];
    scale[c] = rs * g * sc;
    shift[c] = beta[c] - sc * md * rs * g;
  }
}

// ---------------------------------------------------------------------------
// BN apply + residual + PReLU + int8 sign-pack.
// ---------------------------------------------------------------------------
__global__ __launch_bounds__(256) void bn_mid(
    const short* __restrict__ dot, const float* __restrict__ x,
    const float* __restrict__ scale, const float* __restrict__ shift,
    const float* __restrict__ pa, float* __restrict__ a1,
    signed char* __restrict__ A) {
  __shared__ short rawd[32 * 264];
  __shared__ float tile[256 * 33];
  __shared__ float ssc[256], ssh[256];
  int t = threadIdx.x;
  int P0 = blockIdx.x * 32;
  ssc[t] = scale[t]; ssh[t] = shift[t];
  float ap = pa[0];
#pragma unroll
  for (int i = 0; i < 4; ++i) {
    int idx = i * 256 + t;
    int pl = idx >> 5, g = idx & 31;
    int4 d = *(const int4*)(dot + (size_t)(P0 + pl) * 256 + g * 8);
    *(int4*)(&rawd[pl * 264 + g * 8]) = d;
  }
  __syncthreads();
  int pl = t & 31, c0 = t >> 5;
  int P = P0 + pl;
  int b = P / HW, hw = P - b * HW;
  size_t base = (size_t)b * (NC * HW) + (size_t)c0 * HW + hw;
#pragma unroll
  for (int i = 0; i < 32; ++i) {
    int c = i * 8 + c0;
    size_t addr = base + (size_t)i * 8 * HW;
    float d = (float)rawd[pl * 264 + c];
    float v = fmaf(d, ssc[c], ssh[c]) + x[addr];
    float o = v >= 0.0f ? v : ap * v;
    a1[addr] = o;
    tile[c * 33 + pl] = o;
  }
  __syncthreads();
  int g = t >> 4, pls = t & 15;
#pragma unroll
  for (int ph = 0; ph < 2; ++ph) {
    int pp = ph * 16 + pls;
    U16 u;
#pragma unroll
    for (int bb = 0; bb < 16; ++bb) {
      float v = tile[(g * 16 + bb) * 33 + pp];
      u.b[bb] = v > 0.f ? 1 : (v < 0.f ? -1 : 0);
    }
    *(int4*)(A + (size_t)(P0 + pp) * 256 + g * 16) = u.v;
  }
}

// ---------------------------------------------------------------------------
// Final: BN apply + residual + PReLU.
// ---------------------------------------------------------------------------
__global__ __launch_bounds__(256) void bn_fin_apply(
    const short* __restrict__ dot, const float* __restrict__ res,
    const float* __restrict__ scale, const float* __restrict__ shift,
    const float* __restrict__ pa, float* __restrict__ out) {
  __shared__ short rawd[32 * 264];
  __shared__ float ssc[256], ssh[256];
  int t = threadIdx.x;
  int P0 = blockIdx.x * 32;
  ssc[t] = scale[t]; ssh[t] = shift[t];
  float ap = pa[0];
#pragma unroll
  for (int i = 0; i < 4; ++i) {
    int idx = i * 256 + t;
    int pl = idx >> 5, g = idx & 31;
    int4 d = *(const int4*)(dot + (size_t)(P0 + pl) * 256 + g * 8);
    *(int4*)(&rawd[pl * 264 + g * 8]) = d;
  }
  __syncthreads();
  int pl = t & 31, c0 = t >> 5;
  int P = P0 + pl;
  int b = P / HW, hw = P - b * HW;
  size_t base = (size_t)b * (NC * HW) + (size_t)c0 * HW + hw;
#pragma unroll
  for (int i = 0; i < 32; ++i) {
    int c = i * 8 + c0;
    size_t addr = base + (size_t)i * 8 * HW;
    float d = (float)rawd[pl * 264 + c];
    float v = fmaf(d, ssc[c], ssh[c]) + res[addr];
    out[addr] = v >= 0.0f ? v : ap * v;
  }
}

// ---------------------------------------------------------------------------
extern "C" void kernel_launch(void* const* d_in, const int* in_sizes, int n_in,
                              void* d_out, int out_size, void* d_ws, size_t ws_size,
                              hipStream_t stream) {
  const float* x   = (const float*)d_in[0];
  const float* w1  = (const float*)d_in[1];
  const float* w2  = (const float*)d_in[2];
  const float* g1  = (const float*)d_in[3];
  const float* b1  = (const float*)d_in[4];
  const float* g2  = (const float*)d_in[5];
  const float* b2  = (const float*)d_in[6];
  const float* pa1 = (const float*)d_in[7];
  const float* pa2 = (const float*)d_in[8];
  float* out = (float*)d_out;

  char* ws = (char*)d_ws;
  short*       dotb = (short*)ws;       ws += (size_t)NPIX * 256 * 2;  // 25.7MB (pre-guard for A)
  signed char* Abuf = (signed char*)ws; ws += (size_t)NPIX * 256;      // 12.85MB
  signed char* Wf1  = (signed char*)ws; ws += 589824;                  // post-guard for A
  signed char* Wf2  = (signed char*)ws; ws += 589824;
  float*       a1   = (float*)ws;       ws += NELEM * 4;               // 51.4MB
  int* pd1 = (int*)ws; ws += 784 * 256 * 4;                            // 0.8MB
  int* pq1 = (int*)ws; ws += 784 * 256 * 4;
  int* pd2 = (int*)ws; ws += 784 * 256 * 4;
  int* pq2 = (int*)ws; ws += 784 * 256 * 4;
  float* alpha1 = (float*)ws; ws += 1024;
  float* alpha2 = (float*)ws; ws += 1024;
  float* scale1 = (float*)ws; ws += 1024;
  float* shift1 = (float*)ws; ws += 1024;
  float* scale2 = (float*)ws; ws += 1024;
  float* shift2 = (float*)ws; ws += 1024;

  alpha_k<<<512, 256, 0, stream>>>(w1, w2, alpha1, alpha2);
  wfrag_k<<<144, 256, 0, stream>>>(w1, w2, Wf1, Wf2);
  pack_x<<<NPIX / 32, 256, 0, stream>>>(x, Abuf);

  conv_mfma<<<784, 256, 0, stream>>>(Abuf, Wf1, dotb, pd1, pq1);
  bn_finalize<<<256, 256, 0, stream>>>(pd1, pq1, alpha1, g1, b1, scale1, shift1);
  bn_mid<<<NPIX / 32, 256, 0, stream>>>(dotb, x, scale1, shift1, pa1, a1, Abuf);

  conv_mfma<<<784, 256, 0, stream>>>(Abuf, Wf2, dotb, pd2, pq2);
  bn_finalize<<<256, 256, 0, stream>>>(pd2, pq2, alpha2, g2, b2, scale2, shift2);
  bn_fin_apply<<<NPIX / 32, 256, 0, stream>>>(dotb, a1, scale2, shift2, pa2, out);
}

// Round 13
// 158.009 us; speedup vs baseline: 1.2414x; 1.2414x over previous
//
#include <hip/hip_runtime.h>
#include <cstdint>

#define NB 64
#define NC 256
#define HW 784              // 28*28
#define NPIX (NB*HW)        // 50176
#define NELEM ((size_t)NB*NC*HW)

#define MTILE 256
#define HALO_ROWS 314       // pixels p0-29 .. p0+284
#define A_BYTES (HALO_ROWS*256)       // 80384
#define ZERO_OFF A_BYTES              // 256B zero row
#define W_LDS_OFF (A_BYTES + 256)     // 80640
#define W_BUF_SZ 32768                // one half-tap (4 cin-chunks x 8 cgroups)
#define CONV_LDS (W_LDS_OFF + 2*W_BUF_SZ)  // 146176

typedef int v4i  __attribute__((ext_vector_type(4)));
typedef int v16i __attribute__((ext_vector_type(16)));

union U16 { signed char b[16]; int4 v; };

__device__ __forceinline__ void gload_lds16(const signed char* src,
                                            signed char* dst) {
  __builtin_amdgcn_global_load_lds(
      (const __attribute__((address_space(1))) void*)src,
      (__attribute__((address_space(3))) void*)dst, 16, 0, 0);
}

// ---------------------------------------------------------------------------
// alpha = mean|w| per (conv, cout).
// ---------------------------------------------------------------------------
__global__ __launch_bounds__(256) void alpha_k(
    const float* __restrict__ w1, const float* __restrict__ w2,
    float* __restrict__ al1, float* __restrict__ al2) {
  int blk = blockIdx.x;
  int conv = blk >> 8, cout = blk & 255;
  const float* w = (conv ? w2 : w1) + (size_t)cout * 2304;
  int t = threadIdx.x;
  float s = 0.0f;
  for (int i = t; i < 2304; i += 256) s += fabsf(w[i]);
  __shared__ float red[256];
  red[t] = s;
  __syncthreads();
  for (int st = 128; st > 0; st >>= 1) {
    if (t < st) red[t] += red[t + st];
    __syncthreads();
  }
  if (t == 0) (conv ? al2 : al1)[cout] = red[0] / 2304.0f;
}

// ---------------------------------------------------------------------------
// Pack weights into MFMA B-fragment order: Wf[tap][chunk(8)][cgroup(8)][lane(64)][16]
// ---------------------------------------------------------------------------
__global__ __launch_bounds__(256) void wfrag_k(
    const float* __restrict__ w1, const float* __restrict__ w2,
    signed char* __restrict__ Wf1, signed char* __restrict__ Wf2) {
  int bi = blockIdx.x;            // 144 = 2 conv x 9 tap x 8 cgroup
  int conv = bi / 72, r = bi % 72, tap = r >> 3, cg = r & 7;
  const float* w = conv ? w2 : w1;
  signed char* Wf = conv ? Wf2 : Wf1;
  int t = threadIdx.x;
  for (int e = t; e < 512; e += 256) {
    int c = e >> 6, lane = e & 63;
    int cout = cg * 32 + (lane & 31);
    int cin0 = c * 32 + (lane >> 5) * 16;
    U16 u;
#pragma unroll
    for (int bb = 0; bb < 16; ++bb) {
      float v = w[((size_t)cout * 256 + cin0 + bb) * 9 + tap];
      u.b[bb] = v > 0.f ? 1 : (v < 0.f ? -1 : 0);
    }
    *(int4*)(Wf + ((((size_t)tap * 8 + c) * 8 + cg) * 64 + lane) * 16) = u.v;
  }
}

// ---------------------------------------------------------------------------
// x (NCHW f32) -> int8 signs, pixel-major [p][256]. LDS transpose, coalesced.
// ---------------------------------------------------------------------------
__global__ __launch_bounds__(256) void pack_x(
    const float* __restrict__ in, signed char* __restrict__ A) {
  __shared__ float tile[256 * 33];
  int t = threadIdx.x;
  int P0 = blockIdx.x * 32;
  int pl = t & 31, c0 = t >> 5;
  int P = P0 + pl;
  int b = P / HW, hw = P - b * HW;
  size_t base = (size_t)b * (NC * HW) + (size_t)c0 * HW + hw;
#pragma unroll
  for (int i = 0; i < 32; ++i)
    tile[(i * 8 + c0) * 33 + pl] = in[base + (size_t)i * 8 * HW];
  __syncthreads();
  int g = t >> 4, pls = t & 15;
#pragma unroll
  for (int ph = 0; ph < 2; ++ph) {
    int pp = ph * 16 + pls;
    U16 u;
#pragma unroll
    for (int bb = 0; bb < 16; ++bb) {
      float v = tile[(g * 16 + bb) * 33 + pp];
      u.b[bb] = v > 0.f ? 1 : (v < 0.f ? -1 : 0);
    }
    *(int4*)(A + (size_t)(P0 + pp) * 256 + g * 16) = u.v;
  }
}

// ---------------------------------------------------------------------------
// int8 MFMA conv 3x3 pad 1 + per-wave i32 BN-stat partials.
// Block: 256 px x 256 co, 512 thr (8 waves = 4M x 2N), grid 196.
// A halo (80KB) staged once. W streams: 18 half-taps x 32KB double-buffered,
// staged via global_load_lds (width 16), COUNTED vmcnt(4) (never 0 in loop),
// raw s_barrier, 32-MFMA cluster per phase wrapped in setprio.
// Invalid taps read a zeroed LDS row.
// ---------------------------------------------------------------------------
__global__ __launch_bounds__(512, 2) void conv_mfma(
    const signed char* __restrict__ A, const signed char* __restrict__ Wf,
    short* __restrict__ dotb,
    int* __restrict__ pd, int* __restrict__ pq) {
  extern __shared__ signed char smem[];
  signed char* As = smem;
  signed char* Wlds = smem + W_LDS_OFF;

  int t = threadIdx.x;
  int lane = t & 63, wid = t >> 6;
  int mblk = blockIdx.x;
  int p0 = mblk * MTILE;
  int wm = wid & 3, wn = wid >> 2;
  int khalf = lane >> 5;

  // stage A halo rows p0-29 .. p0+284 with granule swizzle (key = pixel&15)
  {
    const signed char* src = A + (size_t)(p0 - 29) * 256;
#pragma unroll
    for (int i = 0; i < 10; ++i) {
      int off = i * 8192 + t * 16;
      if (off < A_BYTES) {
        int4 d = *(const int4*)(src + off);
        int r = off >> 8, g = (off >> 4) & 15;
        int gs = g ^ ((r + 3) & 15);    // (p0-29+r)&15 with p0%16==0
        *(int4*)(As + r * 256 + gs * 16) = d;
      }
    }
    if (t < 16) { int4 z = {0, 0, 0, 0}; *(int4*)(As + ZERO_OFF + t * 16) = z; }
  }

  // per-lane pixel geometry for this wave's 2 M-fragments
  int prow[2], hh[2], ww[2];
#pragma unroll
  for (int i = 0; i < 2; ++i) {
    int p = p0 + wm * 64 + i * 32 + (lane & 31);
    prow[i] = p;
    int hw = p % HW;
    hh[i] = hw / 28;
    ww[i] = hw - hh[i] * 28;
  }
  __syncthreads();   // A staged; also drains A's global loads (vmcnt back to 0)

  // prologue: issue W loads for half-taps 0 and 1 (4 x 1KB per wave each)
#pragma unroll
  for (int h = 0; h < 2; ++h) {
    const signed char* wsrc = Wf + (size_t)h * W_BUF_SZ + wid * 4096 + lane * 16;
    signed char* wdst = Wlds + h * W_BUF_SZ + wid * 4096;
#pragma unroll
    for (int j = 0; j < 4; ++j)
      gload_lds16(wsrc + j * 1024, wdst + j * 1024);
  }

  v16i acc[2][4];
#pragma unroll
  for (int i = 0; i < 2; ++i)
#pragma unroll
    for (int j = 0; j < 4; ++j) { v16i z = {0}; acc[i][j] = z; }

  int rb0 = 0, rb1 = 0, kk0 = 0, kk1 = 0;

#pragma unroll
  for (int h = 0; h < 18; ++h) {      // half-tap h = tap*2 + half
    // wait own outstanding W loads down to the next half-tap's 4; sync waves
    if (h < 17) asm volatile("s_waitcnt vmcnt(4)" ::: "memory");
    else        asm volatile("s_waitcnt vmcnt(0)" ::: "memory");
    __builtin_amdgcn_s_barrier();

    // new tap: compute A address tables
    if ((h & 1) == 0) {
      const int tap = h >> 1;
      const int ky = (tap >= 3) + (tap >= 6);
      const int kx = tap - 3 * ky;
      const int dlt = (ky - 1) * 28 + (kx - 1);
      int hp = hh[0] + ky - 1, wp = ww[0] + kx - 1;
      bool val = ((unsigned)hp < 28u) && ((unsigned)wp < 28u);
      int pr = prow[0] + dlt;
      rb0 = val ? (pr - (p0 - 29)) * 256 : ZERO_OFF;
      kk0 = val ? ((pr & 15) << 4) : 0;
      hp = hh[1] + ky - 1; wp = ww[1] + kx - 1;
      val = ((unsigned)hp < 28u) && ((unsigned)wp < 28u);
      pr = prow[1] + dlt;
      rb1 = val ? (pr - (p0 - 29)) * 256 : ZERO_OFF;
      kk1 = val ? ((pr & 15) << 4) : 0;
    }

    // 32-MFMA cluster over the 4 cin-chunks of this half-tap (LDS only)
    const signed char* wbuf = Wlds + (h & 1) * W_BUF_SZ;
    __builtin_amdgcn_s_setprio(1);
#pragma unroll
    for (int cl = 0; cl < 4; ++cl) {
      const int chunk = (h & 1) * 4 + cl;
      const int gl4 = ((chunk * 2 + khalf) << 4);
      v4i a0 = *(const v4i*)(As + rb0 + (gl4 ^ kk0));
      v4i a1 = *(const v4i*)(As + rb1 + (gl4 ^ kk1));
      const signed char* wb = wbuf + cl * 8192 + wn * 4096 + lane * 16;
      v4i w0 = *(const v4i*)(wb);
      v4i w1 = *(const v4i*)(wb + 1024);
      v4i w2 = *(const v4i*)(wb + 2048);
      v4i w3 = *(const v4i*)(wb + 3072);
      acc[0][0] = __builtin_amdgcn_mfma_i32_32x32x32_i8(a0, w0, acc[0][0], 0, 0, 0);
      acc[0][1] = __builtin_amdgcn_mfma_i32_32x32x32_i8(a0, w1, acc[0][1], 0, 0, 0);
      acc[0][2] = __builtin_amdgcn_mfma_i32_32x32x32_i8(a0, w2, acc[0][2], 0, 0, 0);
      acc[0][3] = __builtin_amdgcn_mfma_i32_32x32x32_i8(a0, w3, acc[0][3], 0, 0, 0);
      acc[1][0] = __builtin_amdgcn_mfma_i32_32x32x32_i8(a1, w0, acc[1][0], 0, 0, 0);
      acc[1][1] = __builtin_amdgcn_mfma_i32_32x32x32_i8(a1, w1, acc[1][1], 0, 0, 0);
      acc[1][2] = __builtin_amdgcn_mfma_i32_32x32x32_i8(a1, w2, acc[1][2], 0, 0, 0);
      acc[1][3] = __builtin_amdgcn_mfma_i32_32x32x32_i8(a1, w3, acc[1][3], 0, 0, 0);
    }
    __builtin_amdgcn_s_setprio(0);
    __builtin_amdgcn_s_barrier();   // all waves done reading buf[h&1]

    // issue W loads for half-tap h+2 into the buffer just freed
    if (h + 2 < 18) {
      const signed char* wsrc =
          Wf + (size_t)(h + 2) * W_BUF_SZ + wid * 4096 + lane * 16;
      signed char* wdst = Wlds + (h & 1) * W_BUF_SZ + wid * 4096;
#pragma unroll
      for (int j = 0; j < 4; ++j)
        gload_lds16(wsrc + j * 1024, wdst + j * 1024);
    }
  }

  // stats: per-cout partial sums of dot and dot^2 over this wave's 64 rows
#pragma unroll
  for (int j = 0; j < 4; ++j) {
    int s = 0, sq = 0;
#pragma unroll
    for (int i = 0; i < 2; ++i)
#pragma unroll
      for (int q = 0; q < 16; ++q) {
        int v = acc[i][j][q];
        s += v; sq += v * v;
      }
    s += __shfl_xor(s, 32); sq += __shfl_xor(sq, 32);
    if (lane < 32) {
      int row = mblk * 4 + wm;
      int co = wn * 128 + j * 32 + lane;
      pd[row * 256 + co] = s;
      pq[row * 256 + co] = sq;
    }
  }

  // store dot int16, pixel-major [p][256]
#pragma unroll
  for (int i = 0; i < 2; ++i) {
    int pr = p0 + wm * 64 + i * 32 + 4 * khalf;
#pragma unroll
    for (int j = 0; j < 4; ++j) {
      int cb = wn * 128 + j * 32;
#pragma unroll
      for (int q = 0; q < 16; ++q) {
        int row = pr + (q & 3) + 8 * (q >> 2);
        dotb[(size_t)row * 256 + cb + (lane & 31)] = (short)acc[i][j][q];
      }
    }
  }
}

// ---------------------------------------------------------------------------
// Finalize BN from i32 partials (784 rows). One block per channel.
// ---------------------------------------------------------------------------
__global__ __launch_bounds__(256) void bn_finalize(
    const int* __restrict__ pd, const int* __restrict__ pq,
    const float* __restrict__ alpha, const float* __restrict__ gamma,
    const float* __restrict__ beta, float* __restrict__ scale,
    float* __restrict__ shift) {
  int c = blockIdx.x, t = threadIdx.x;
  long long D = 0, D2 = 0;
  for (int r = t; r < 784; r += 256) {
    D  += (long long)pd[r * 256 + c];
    D2 += (long long)pq[r * 256 + c];
  }
  __shared__ long long rd[256], rq[256];
  rd[t] = D; rq[t] = D2;
  __syncthreads();
  for (int st = 128; st > 0; st >>= 1) {
    if (t < st) { rd[t] += rd[t + st]; rq[t] += rq[t + st]; }
    __syncthreads();
  }
  if (t == 0) {
    float sc = 0.1f * alpha[c];
    const float invN = 1.0f / (float)(NB * HW);
    float md  = (float)rd[0] * invN;
    float ex2 = (float)rq[0] * invN;
    float var = sc * sc * (ex2 - md * md);
    float rs = rsqrtf(var + 1e-5f);
    float g = gamma[c];
    scale[c] = rs * g * sc;
    shift[c] = beta[c] - sc * md * rs * g;
  }
}

// ---------------------------------------------------------------------------
// BN apply + residual + PReLU + int8 sign-pack.
// ---------------------------------------------------------------------------
__global__ __launch_bounds__(256) void bn_mid(
    const short* __restrict__ dot, const float* __restrict__ x,
    const float* __restrict__ scale, const float* __restrict__ shift,
    const float* __restrict__ pa, float* __restrict__ a1,
    signed char* __restrict__ A) {
  __shared__ short rawd[32 * 264];
  __shared__ float tile[256 * 33];
  __shared__ float ssc[256], ssh[256];
  int t = threadIdx.x;
  int P0 = blockIdx.x * 32;
  ssc[t] = scale[t]; ssh[t] = shift[t];
  float ap = pa[0];
#pragma unroll
  for (int i = 0; i < 4; ++i) {
    int idx = i * 256 + t;
    int pl = idx >> 5, g = idx & 31;
    int4 d = *(const int4*)(dot + (size_t)(P0 + pl) * 256 + g * 8);
    *(int4*)(&rawd[pl * 264 + g * 8]) = d;
  }
  __syncthreads();
  int pl = t & 31, c0 = t >> 5;
  int P = P0 + pl;
  int b = P / HW, hw = P - b * HW;
  size_t base = (size_t)b * (NC * HW) + (size_t)c0 * HW + hw;
#pragma unroll
  for (int i = 0; i < 32; ++i) {
    int c = i * 8 + c0;
    size_t addr = base + (size_t)i * 8 * HW;
    float d = (float)rawd[pl * 264 + c];
    float v = fmaf(d, ssc[c], ssh[c]) + x[addr];
    float o = v >= 0.0f ? v : ap * v;
    a1[addr] = o;
    tile[c * 33 + pl] = o;
  }
  __syncthreads();
  int g = t >> 4, pls = t & 15;
#pragma unroll
  for (int ph = 0; ph < 2; ++ph) {
    int pp = ph * 16 + pls;
    U16 u;
#pragma unroll
    for (int bb = 0; bb < 16; ++bb) {
      float v = tile[(g * 16 + bb) * 33 + pp];
      u.b[bb] = v > 0.f ? 1 : (v < 0.f ? -1 : 0);
    }
    *(int4*)(A + (size_t)(P0 + pp) * 256 + g * 16) = u.v;
  }
}

// ---------------------------------------------------------------------------
// Final: BN apply + residual + PReLU.
// ---------------------------------------------------------------------------
__global__ __launch_bounds__(256) void bn_fin_apply(
    const short* __restrict__ dot, const float* __restrict__ res,
    const float* __restrict__ scale, const float* __restrict__ shift,
    const float* __restrict__ pa, float* __restrict__ out) {
  __shared__ short rawd[32 * 264];
  __shared__ float ssc[256], ssh[256];
  int t = threadIdx.x;
  int P0 = blockIdx.x * 32;
  ssc[t] = scale[t]; ssh[t] = shift[t];
  float ap = pa[0];
#pragma unroll
  for (int i = 0; i < 4; ++i) {
    int idx = i * 256 + t;
    int pl = idx >> 5, g = idx & 31;
    int4 d = *(const int4*)(dot + (size_t)(P0 + pl) * 256 + g * 8);
    *(int4*)(&rawd[pl * 264 + g * 8]) = d;
  }
  __syncthreads();
  int pl = t & 31, c0 = t >> 5;
  int P = P0 + pl;
  int b = P / HW, hw = P - b * HW;
  size_t base = (size_t)b * (NC * HW) + (size_t)c0 * HW + hw;
#pragma unroll
  for (int i = 0; i < 32; ++i) {
    int c = i * 8 + c0;
    size_t addr = base + (size_t)i * 8 * HW;
    float d = (float)rawd[pl * 264 + c];
    float v = fmaf(d, ssc[c], ssh[c]) + res[addr];
    out[addr] = v >= 0.0f ? v : ap * v;
  }
}

// ---------------------------------------------------------------------------
extern "C" void kernel_launch(void* const* d_in, const int* in_sizes, int n_in,
                              void* d_out, int out_size, void* d_ws, size_t ws_size,
                              hipStream_t stream) {
  const float* x   = (const float*)d_in[0];
  const float* w1  = (const float*)d_in[1];
  const float* w2  = (const float*)d_in[2];
  const float* g1  = (const float*)d_in[3];
  const float* b1  = (const float*)d_in[4];
  const float* g2  = (const float*)d_in[5];
  const float* b2  = (const float*)d_in[6];
  const float* pa1 = (const float*)d_in[7];
  const float* pa2 = (const float*)d_in[8];
  float* out = (float*)d_out;

  char* ws = (char*)d_ws;
  short*       dotb = (short*)ws;       ws += (size_t)NPIX * 256 * 2;  // 25.7MB (pre-guard for A)
  signed char* Abuf = (signed char*)ws; ws += (size_t)NPIX * 256;      // 12.85MB
  signed char* Wf1  = (signed char*)ws; ws += 589824;                  // post-guard for A
  signed char* Wf2  = (signed char*)ws; ws += 589824;
  float*       a1   = (float*)ws;       ws += NELEM * 4;               // 51.4MB
  int* pd1 = (int*)ws; ws += 784 * 256 * 4;                            // 0.8MB
  int* pq1 = (int*)ws; ws += 784 * 256 * 4;
  int* pd2 = (int*)ws; ws += 784 * 256 * 4;
  int* pq2 = (int*)ws; ws += 784 * 256 * 4;
  float* alpha1 = (float*)ws; ws += 1024;
  float* alpha2 = (float*)ws; ws += 1024;
  float* scale1 = (float*)ws; ws += 1024;
  float* shift1 = (float*)ws; ws += 1024;
  float* scale2 = (float*)ws; ws += 1024;
  float* shift2 = (float*)ws; ws += 1024;

  static int attr_done = 0;
  if (!attr_done) {
    hipFuncSetAttribute((const void*)conv_mfma,
                        hipFuncAttributeMaxDynamicSharedMemorySize, CONV_LDS);
    attr_done = 1;
  }

  alpha_k<<<512, 256, 0, stream>>>(w1, w2, alpha1, alpha2);
  wfrag_k<<<144, 256, 0, stream>>>(w1, w2, Wf1, Wf2);
  pack_x<<<NPIX / 32, 256, 0, stream>>>(x, Abuf);

  conv_mfma<<<196, 512, CONV_LDS, stream>>>(Abuf, Wf1, dotb, pd1, pq1);
  bn_finalize<<<256, 256, 0, stream>>>(pd1, pq1, alpha1, g1, b1, scale1, shift1);
  bn_mid<<<NPIX / 32, 256, 0, stream>>>(dotb, x, scale1, shift1, pa1, a1, Abuf);

  conv_mfma<<<196, 512, CONV_LDS, stream>>>(Abuf, Wf2, dotb, pd2, pq2);
  bn_finalize<<<256, 256, 0, stream>>>(pd2, pq2, alpha2, g2, b2, scale2, shift2);
  bn_fin_apply<<<NPIX / 32, 256, 0, stream>>>(dotb, a1, scale2, shift2, pa2, out);
}